// Round 22
// baseline (143.021 us; speedup 1.0000x reference)
//
#include <hip/hip_runtime.h>

// Problem constants (fixed by setup_inputs)
#define B   8
#define C   256
#define H   128
#define W   128
#define HW  (H * W)
#define FH  512
#define FW  512

// Tiling
#define TR     16              // output rows per tile
#define SLOTS  24              // staged row slots (= 12 wave-chunks of 2 rows)
#define HALO   3               // rows staged above tile: row0 = ybase-3
#define CG     16              // channels per block (8 pairs)
#define RGN    (H / TR)        // 8 row-groups
#define CGN    (C / CG)        // 16 channel-groups
#define NT     512             // threads per block

// 8B LDS load at 4B alignment -> ds_read2_b32 (one instruction).
struct __attribute__((packed, aligned(4))) pf2 { float x, y; };
typedef float f32x2v __attribute__((ext_vector_type(2)));

// ---------------------------------------------------------------------------
// Inline flow downsample: f[b,:,y,x] of the reference, computed on the fly.
// Per pixel: 8 float4 loads (L2/L3-hot flows) + 64 FMA; conv_w reads are
// wave-uniform -> scalar loads.
// ---------------------------------------------------------------------------
__device__ __forceinline__ void flow_at(
    const float* __restrict__ flows, const float* __restrict__ cw,
    int bb, int x, int y, float& fx, float& fy)
{
    const float* p0 = flows + ((size_t)bb * 2 + 0) * FH * FW
                    + (size_t)(4 * y) * FW + 4 * x;
    const float* p1 = p0 + (size_t)FH * FW;
    float ax = 0.f, ay = 0.f;
#pragma unroll
    for (int kh = 0; kh < 4; ++kh) {
        const float4 v0 = *reinterpret_cast<const float4*>(p0 + kh * FW);
        const float4 v1 = *reinterpret_cast<const float4*>(p1 + kh * FW);
        const float* w00 = cw + 0 * 16 + kh * 4;   // o=0,i=0
        const float* w01 = cw + 1 * 16 + kh * 4;   // o=0,i=1
        const float* w10 = cw + 2 * 16 + kh * 4;   // o=1,i=0
        const float* w11 = cw + 3 * 16 + kh * 4;   // o=1,i=1
        ax += v0.x * w00[0] + v0.y * w00[1] + v0.z * w00[2] + v0.w * w00[3]
            + v1.x * w01[0] + v1.y * w01[1] + v1.z * w01[2] + v1.w * w01[3];
        ay += v0.x * w10[0] + v0.y * w10[1] + v0.z * w10[2] + v0.w * w10[3]
            + v1.x * w11[0] + v1.y * w11[1] + v1.z * w11[2] + v1.w * w11[3];
    }
    fx = ax; fy = ay;
}

// ---------------------------------------------------------------------------
// Fused bilinear warp (R20 structure + inline flow conv; no separate
// downsample kernel, no workspace round-trip, single dispatch).
// ---------------------------------------------------------------------------
#define GLOAD_LDS(gsrc, ldst)                                                 \
    __builtin_amdgcn_global_load_lds(                                         \
        (const __attribute__((address_space(1))) void*)(gsrc),                \
        (__attribute__((address_space(3))) void*)(ldst), 16, 0, 0)

__global__ __launch_bounds__(NT, 6) void warp_kernel(
    const float* __restrict__ feat,
    const float* __restrict__ flows,
    const float* __restrict__ conv_w,
    float* __restrict__ out)
{
    // [super-buffer][channel-within-pair][24 rows x 128] linear planes
    __shared__ __align__(16) float rows[2][2][SLOTS * W];  // 49152 B

    // XCD-chunked swizzle (1024 blocks = 8 XCDs x 128), rg fastest.
    const int hw_bid = blockIdx.x;
    const int lin = (hw_bid & 7) * 128 + (hw_bid >> 3);
    const int rg = lin & (RGN - 1);
    const int cg = (lin >> 3) & (CGN - 1);
    const int b  = lin >> 7;

    const int tid  = threadIdx.x;
    const int lane = tid & 63;
    const int wv   = tid >> 6;          // 0..7
    const int wq   = wv & 3;            // wave within channel-half
    const int half = wv >> 2;           // 0: channel A, 1: channel B

    const int ybase = rg * TR;
    const int row0  = ybase - HALO;
    const int pixbase = ybase * W;

    const float* featb = feat + ((size_t)b * C + (size_t)cg * CG) * HW;
    float*       outc  = out  + ((size_t)b * C + (size_t)cg * CG) * HW + pixbase;

    // Per-lane global source offsets for this wave's 3 staging chunks.
    int goffs0, goffs1, goffs2;
    {
        const int wc0 = wq * 3 + 0, wc1 = wq * 3 + 1, wc2 = wq * 3 + 2;
        const int r0c = min(max(row0 + 2 * wc0 + (lane >> 5), 0), H - 1);
        const int r1c = min(max(row0 + 2 * wc1 + (lane >> 5), 0), H - 1);
        const int r2c = min(max(row0 + 2 * wc2 + (lane >> 5), 0), H - 1);
        goffs0 = r0c * W + (lane & 31) * 4;
        goffs1 = r1c * W + (lane & 31) * 4;
        goffs2 = r2c * W + (lane & 31) * 4;
    }

#define PREF2(s, chA) do {                                                    \
        const float* _cb = featb + (size_t)((chA) + half) * HW;               \
        float* _pl = &rows[(s)][half][0];                                     \
        GLOAD_LDS(_cb + goffs0, _pl + (wq * 3 + 0) * 256);                    \
        GLOAD_LDS(_cb + goffs1, _pl + (wq * 3 + 1) * 256);                    \
        GLOAD_LDS(_cb + goffs2, _pl + (wq * 3 + 2) * 256);                    \
    } while (0)

    // ---- prologue: pair-0 DMA in flight; fused flow conv + weights under it
    PREF2(0, 0);

    // Pixel mapping: k=0 -> 2t, k=1 -> 2t+1, k=2 -> 1024+2t, k=3 -> 1025+2t.
#define PXOF(k) (((k) >> 1) * 1024 + 2 * tid + ((k) & 1))

    // Named per-pixel state (no arrays -> guaranteed registers).
#define PXDECL(k) int i0_##k, i1_##k; float w0_##k, w1_##k, w2_##k, w3_##k;
    PXDECL(0) PXDECL(1) PXDECL(2) PXDECL(3)

#define WCOMP(k) do {                                                         \
        const int px  = PXOF(k);                                              \
        const int gpx = pixbase + px;                                         \
        const int x = gpx & (W - 1);                                          \
        const int y = gpx >> 7;                                               \
        float fxv, fyv;                                                       \
        flow_at(flows, conv_w, b, x, y, fxv, fyv);                            \
        const float gx = (float)x + fxv;                                      \
        const float gy = (float)y + fyv;                                      \
        const float x0f = floorf(gx);                                         \
        const float y0f = floorf(gy);                                         \
        const float wx = gx - x0f;                                            \
        const float wy = gy - y0f;                                            \
        const int x0 = (int)x0f, y0 = (int)y0f;                               \
        const int y1 = y0 + 1;                                                \
        const float u0 = 1.f - wx, u1 = wx;                                   \
        float A, Bv;                                                          \
        if (x0 >= 0 && x0 <= W - 2)      { A = u0;  Bv = u1;  }               \
        else if (x0 == W - 1)            { A = 0.f; Bv = u0;  }               \
        else if (x0 == -1)               { A = u1;  Bv = 0.f; }               \
        else                             { A = 0.f; Bv = 0.f; }               \
        const int bx = min(max(x0, 0), W - 2);                                \
        const float vy0 = (y0 >= 0 && y0 < H) ? 1.f : 0.f;                    \
        const float vy1 = (y1 >= 0 && y1 < H) ? 1.f : 0.f;                    \
        const int cy0 = min(max(y0, 0), H - 1);                               \
        const int cy1 = min(max(y1, 0), H - 1);                               \
        const int s0 = cy0 - row0;                                            \
        const int s1 = cy1 - row0;                                            \
        const bool ok = (s0 >= 0) && (s1 < SLOTS);                            \
        const int cs0 = min(max(s0, 0), SLOTS - 1);                           \
        const int cs1 = min(max(s1, 0), SLOTS - 1);                           \
        i0_##k = (cs0 * W + bx) | (ok ? 0 : (int)0x80000000);                 \
        i1_##k = cs1 * W + bx;                                                \
        const float wy0 = (1.f - wy) * vy0;                                   \
        const float wy1 = wy * vy1;                                           \
        w0_##k = A * wy0;  w1_##k = Bv * wy0;                                 \
        w2_##k = A * wy1;  w3_##k = Bv * wy1;                                 \
    } while (0)

    WCOMP(0); WCOMP(1); WCOMP(2); WCOMP(3);

    const int anybad = ((i0_0 | i0_1 | i0_2 | i0_3) < 0);

    asm volatile("s_waitcnt vmcnt(0)" ::: "memory");
    __builtin_amdgcn_sched_barrier(0);
    __syncthreads();

    // Fast path, one x-pair (j=0 -> k0,k1 at px 2t; j=1 -> k2,k3 at 1024+2t):
    // 8 paired LDS taps -> 2 NT f32x2 stores (A and B channels).
#define FQUAD(j, k0, k1, rbA, rbB, ocA, ocB) do {                             \
        const int pxe = (j) * 1024 + 2 * tid;                                 \
        const pf2 a0 = *reinterpret_cast<const pf2*>(&rbA[i0_##k0]);          \
        const pf2 a1 = *reinterpret_cast<const pf2*>(&rbA[i1_##k0]);          \
        const pf2 c0 = *reinterpret_cast<const pf2*>(&rbA[i0_##k1]);          \
        const pf2 c1 = *reinterpret_cast<const pf2*>(&rbA[i1_##k1]);          \
        const pf2 d0 = *reinterpret_cast<const pf2*>(&rbB[i0_##k0]);          \
        const pf2 d1 = *reinterpret_cast<const pf2*>(&rbB[i1_##k0]);          \
        const pf2 e0 = *reinterpret_cast<const pf2*>(&rbB[i0_##k1]);          \
        const pf2 e1 = *reinterpret_cast<const pf2*>(&rbB[i1_##k1]);          \
        f32x2v vA, vB;                                                        \
        vA.x = a0.x * w0_##k0 + a0.y * w1_##k0 + a1.x * w2_##k0 + a1.y * w3_##k0; \
        vA.y = c0.x * w0_##k1 + c0.y * w1_##k1 + c1.x * w2_##k1 + c1.y * w3_##k1; \
        vB.x = d0.x * w0_##k0 + d0.y * w1_##k0 + d1.x * w2_##k0 + d1.y * w3_##k0; \
        vB.y = e0.x * w0_##k1 + e0.y * w1_##k1 + e1.x * w2_##k1 + e1.y * w3_##k1; \
        __builtin_nontemporal_store(vA, reinterpret_cast<f32x2v*>(ocA + pxe));\
        __builtin_nontemporal_store(vB, reinterpret_cast<f32x2v*>(ocB + pxe));\
    } while (0)

    // Slow path (never taken for this data): global bilinear gather with
    // inline flow recompute.
#define SPX2(k, ocA, ocB, chA) do {                                           \
        const int px = PXOF(k);                                               \
        const int gpx = pixbase + px;                                         \
        const int x = gpx & (W - 1);                                          \
        const int y = gpx >> 7;                                               \
        float fxv, fyv;                                                       \
        flow_at(flows, conv_w, b, x, y, fxv, fyv);                            \
        const int x0 = (int)floorf((float)x + fxv);                           \
        const int y0 = (int)floorf((float)y + fyv);                           \
        const int bx  = min(max(x0, 0), W - 2);                               \
        const int cy0 = min(max(y0, 0), H - 1);                               \
        const int cy1 = min(max(y0 + 1, 0), H - 1);                           \
        const float* fA = featb + (size_t)(chA) * HW;                         \
        const float* fB = fA + HW;                                            \
        ocA[px] = fA[cy0 * W + bx]     * w0_##k + fA[cy0 * W + bx + 1] * w1_##k\
                + fA[cy1 * W + bx]     * w2_##k + fA[cy1 * W + bx + 1] * w3_##k;\
        ocB[px] = fB[cy0 * W + bx]     * w0_##k + fB[cy0 * W + bx + 1] * w1_##k\
                + fB[cy1 * W + bx]     * w2_##k + fB[cy1 * W + bx + 1] * w3_##k;\
    } while (0)

    // ---- pair loop: DMA(p+1) || compute(p) ; counted vmcnt ; barrier
    for (int p = 0; p < CG / 2; ++p) {
        const int chA = 2 * p;
        if (p < CG / 2 - 1) PREF2((p + 1) & 1, chA + 2);

        const float* rbA = &rows[p & 1][0][0];
        const float* rbB = &rows[p & 1][1][0];
        float* ocA = outc + (size_t)chA * HW;
        float* ocB = ocA + HW;
        if (__builtin_expect(anybad, 0)) {
            SPX2(0, ocA, ocB, chA); SPX2(1, ocA, ocB, chA);
            SPX2(2, ocA, ocB, chA); SPX2(3, ocA, ocB, chA);
        } else {
            FQUAD(0, 0, 1, rbA, rbB, ocA, ocB);
            FQUAD(1, 2, 3, rbA, rbB, ocA, ocB);
        }

        if (p < CG / 2 - 1) {
            // Per-wave issue order: (<=4 prior stores) then 3 DMAs then 4 new
            // stores. vmcnt(4) drains prior stores + all DMAs, leaves the 4
            // current stores in flight (minimal correct wait).
            asm volatile("s_waitcnt vmcnt(4)" ::: "memory");
            __builtin_amdgcn_sched_barrier(0);
            __syncthreads();
        }
    }
#undef PREF2
#undef PXDECL
#undef PXOF
#undef WCOMP
#undef FQUAD
#undef SPX2
}

// ---------------------------------------------------------------------------
extern "C" void kernel_launch(void* const* d_in, const int* in_sizes, int n_in,
                              void* d_out, int out_size, void* d_ws, size_t ws_size,
                              hipStream_t stream)
{
    const float* features = (const float*)d_in[0];
    const float* flows    = (const float*)d_in[1];
    const float* conv_w   = (const float*)d_in[2];
    float*       out      = (float*)d_out;

    // Single fused dispatch: B * RGN * CGN = 1024 blocks of 512 threads.
    warp_kernel<<<1024, NT, 0, stream>>>(features, flows, conv_w, out);
}

// Round 23
// 50.826 us; speedup vs baseline: 2.8139x; 2.8139x over previous
//
#include <hip/hip_runtime.h>

// Problem constants (fixed by setup_inputs)
#define B   8
#define C   256
#define H   128
#define W   128
#define HW  (H * W)
#define FH  512
#define FW  512

// Tiling
#define TR     16              // output rows per tile
#define SLOTS  24              // staged row slots (= 12 wave-chunks of 2 rows)
#define HALO   3               // rows staged above tile: row0 = ybase-3
#define CG     32              // channels per block (16 pairs)
#define RGN    (H / TR)        // 8 row-groups
#define CGN    (C / CG)        // 8 channel-groups
#define NT     512             // threads per block

// 8B LDS load at 4B alignment -> ds_read2_b32 (one instruction).
struct __attribute__((packed, aligned(4))) pf2 { float x, y; };
typedef float f32x2v __attribute__((ext_vector_type(2)));

// ---------------------------------------------------------------------------
// Kernel 1: strided 4x4 conv downsample of flows using runtime conv_w.
// ---------------------------------------------------------------------------
__global__ __launch_bounds__(256) void downsample_kernel(
    const float* __restrict__ flows,
    const float* __restrict__ conv_w,
    float* __restrict__ f)
{
    int idx = blockIdx.x * blockDim.x + threadIdx.x;
    if (idx >= B * 2 * H * W) return;
    int x = idx & (W - 1);
    int y = (idx >> 7) & (H - 1);
    int o = (idx >> 14) & 1;
    int b = idx >> 15;

    const float* fb = flows + (size_t)b * 2 * FH * FW;
    const float* cw = conv_w + o * 2 * 16;

    float acc = 0.f;
#pragma unroll
    for (int i = 0; i < 2; ++i) {
        const float* fi = fb + (size_t)i * FH * FW;
#pragma unroll
        for (int kh = 0; kh < 4; ++kh) {
            const float4 v = *reinterpret_cast<const float4*>(
                fi + (size_t)(4 * y + kh) * FW + 4 * x);
            const float* w = cw + i * 16 + kh * 4;
            acc += v.x * w[0] + v.y * w[1] + v.z * w[2] + v.w * w[3];
        }
    }
    f[idx] = acc;
}

// ---------------------------------------------------------------------------
// Kernel 2: bilinear warp. R20 pair-pipeline (global_load_lds staging,
// 512 threads, 1 barrier/pair, counted vmcnt(4), x-pair f32x2 NT streaming)
// with CG=32: 512 blocks (all resident at 2/CU, zero tail), WCOMP prologue
// and its vmcnt(0) drain amortized over 2x channels.
// ---------------------------------------------------------------------------
#define GLOAD_LDS(gsrc, ldst)                                                 \
    __builtin_amdgcn_global_load_lds(                                         \
        (const __attribute__((address_space(1))) void*)(gsrc),                \
        (__attribute__((address_space(3))) void*)(ldst), 16, 0, 0)

__global__ __launch_bounds__(NT, 6) void warp_kernel(
    const float* __restrict__ feat,
    const float* __restrict__ f,
    float* __restrict__ out)
{
    // [super-buffer][channel-within-pair][24 rows x 128] linear planes
    __shared__ __align__(16) float rows[2][2][SLOTS * W];  // 49152 B

    // XCD-chunked swizzle (512 blocks = 8 XCDs x 64), rg fastest.
    const int hw_bid = blockIdx.x;
    const int lin = (hw_bid & 7) * 64 + (hw_bid >> 3);
    const int rg = lin & (RGN - 1);
    const int cg = (lin >> 3) & (CGN - 1);
    const int b  = lin >> 6;

    const int tid  = threadIdx.x;
    const int lane = tid & 63;
    const int wv   = tid >> 6;          // 0..7
    const int wq   = wv & 3;            // wave within channel-half
    const int half = wv >> 2;           // 0: channel A, 1: channel B

    const int ybase = rg * TR;
    const int row0  = ybase - HALO;
    const int pixbase = ybase * W;

    const float* featb = feat + ((size_t)b * C + (size_t)cg * CG) * HW;
    float*       outc  = out  + ((size_t)b * C + (size_t)cg * CG) * HW + pixbase;
    const float* fx_p  = f + (size_t)(b * 2 + 0) * HW;
    const float* fy_p  = f + (size_t)(b * 2 + 1) * HW;

    // Per-lane global source offsets for this wave's 3 staging chunks.
    int goffs0, goffs1, goffs2;
    {
        const int wc0 = wq * 3 + 0, wc1 = wq * 3 + 1, wc2 = wq * 3 + 2;
        const int r0c = min(max(row0 + 2 * wc0 + (lane >> 5), 0), H - 1);
        const int r1c = min(max(row0 + 2 * wc1 + (lane >> 5), 0), H - 1);
        const int r2c = min(max(row0 + 2 * wc2 + (lane >> 5), 0), H - 1);
        goffs0 = r0c * W + (lane & 31) * 4;
        goffs1 = r1c * W + (lane & 31) * 4;
        goffs2 = r2c * W + (lane & 31) * 4;
    }

#define PREF2(s, chA) do {                                                    \
        const float* _cb = featb + (size_t)((chA) + half) * HW;               \
        float* _pl = &rows[(s)][half][0];                                     \
        GLOAD_LDS(_cb + goffs0, _pl + (wq * 3 + 0) * 256);                    \
        GLOAD_LDS(_cb + goffs1, _pl + (wq * 3 + 1) * 256);                    \
        GLOAD_LDS(_cb + goffs2, _pl + (wq * 3 + 2) * 256);                    \
    } while (0)

    // ---- prologue: pair-0 DMA in flight; weights -> registers meanwhile
    PREF2(0, 0);

    // Pixel mapping: k=0 -> 2t, k=1 -> 2t+1, k=2 -> 1024+2t, k=3 -> 1025+2t.
#define PXOF(k) (((k) >> 1) * 1024 + 2 * tid + ((k) & 1))

    // Named per-pixel state (no arrays -> guaranteed registers).
#define PXDECL(k) int i0_##k, i1_##k; float w0_##k, w1_##k, w2_##k, w3_##k;
    PXDECL(0) PXDECL(1) PXDECL(2) PXDECL(3)

#define WCOMP(k) do {                                                         \
        const int px  = PXOF(k);                                              \
        const int gpx = pixbase + px;                                         \
        const int x = gpx & (W - 1);                                          \
        const int y = gpx >> 7;                                               \
        const float gx = (float)x + fx_p[gpx];                                \
        const float gy = (float)y + fy_p[gpx];                                \
        const float x0f = floorf(gx);                                         \
        const float y0f = floorf(gy);                                         \
        const float wx = gx - x0f;                                            \
        const float wy = gy - y0f;                                            \
        const int x0 = (int)x0f, y0 = (int)y0f;                               \
        const int y1 = y0 + 1;                                                \
        const float u0 = 1.f - wx, u1 = wx;                                   \
        float A, Bv;                                                          \
        if (x0 >= 0 && x0 <= W - 2)      { A = u0;  Bv = u1;  }               \
        else if (x0 == W - 1)            { A = 0.f; Bv = u0;  }               \
        else if (x0 == -1)               { A = u1;  Bv = 0.f; }               \
        else                             { A = 0.f; Bv = 0.f; }               \
        const int bx = min(max(x0, 0), W - 2);                                \
        const float vy0 = (y0 >= 0 && y0 < H) ? 1.f : 0.f;                    \
        const float vy1 = (y1 >= 0 && y1 < H) ? 1.f : 0.f;                    \
        const int cy0 = min(max(y0, 0), H - 1);                               \
        const int cy1 = min(max(y1, 0), H - 1);                               \
        const int s0 = cy0 - row0;                                            \
        const int s1 = cy1 - row0;                                            \
        const bool ok = (s0 >= 0) && (s1 < SLOTS);                            \
        const int cs0 = min(max(s0, 0), SLOTS - 1);                           \
        const int cs1 = min(max(s1, 0), SLOTS - 1);                           \
        i0_##k = (cs0 * W + bx) | (ok ? 0 : (int)0x80000000);                 \
        i1_##k = cs1 * W + bx;                                                \
        const float wy0 = (1.f - wy) * vy0;                                   \
        const float wy1 = wy * vy1;                                           \
        w0_##k = A * wy0;  w1_##k = Bv * wy0;                                 \
        w2_##k = A * wy1;  w3_##k = Bv * wy1;                                 \
    } while (0)

    WCOMP(0); WCOMP(1); WCOMP(2); WCOMP(3);

    const int anybad = ((i0_0 | i0_1 | i0_2 | i0_3) < 0);

    asm volatile("s_waitcnt vmcnt(0)" ::: "memory");
    __builtin_amdgcn_sched_barrier(0);
    __syncthreads();

    // Fast path, one x-pair (j=0 -> k0,k1 at px 2t; j=1 -> k2,k3 at 1024+2t):
    // 8 paired LDS taps -> 2 NT f32x2 stores (A and B channels).
#define FQUAD(j, k0, k1, rbA, rbB, ocA, ocB) do {                             \
        const int pxe = (j) * 1024 + 2 * tid;                                 \
        const pf2 a0 = *reinterpret_cast<const pf2*>(&rbA[i0_##k0]);          \
        const pf2 a1 = *reinterpret_cast<const pf2*>(&rbA[i1_##k0]);          \
        const pf2 c0 = *reinterpret_cast<const pf2*>(&rbA[i0_##k1]);          \
        const pf2 c1 = *reinterpret_cast<const pf2*>(&rbA[i1_##k1]);          \
        const pf2 d0 = *reinterpret_cast<const pf2*>(&rbB[i0_##k0]);          \
        const pf2 d1 = *reinterpret_cast<const pf2*>(&rbB[i1_##k0]);          \
        const pf2 e0 = *reinterpret_cast<const pf2*>(&rbB[i0_##k1]);          \
        const pf2 e1 = *reinterpret_cast<const pf2*>(&rbB[i1_##k1]);          \
        f32x2v vA, vB;                                                        \
        vA.x = a0.x * w0_##k0 + a0.y * w1_##k0 + a1.x * w2_##k0 + a1.y * w3_##k0; \
        vA.y = c0.x * w0_##k1 + c0.y * w1_##k1 + c1.x * w2_##k1 + c1.y * w3_##k1; \
        vB.x = d0.x * w0_##k0 + d0.y * w1_##k0 + d1.x * w2_##k0 + d1.y * w3_##k0; \
        vB.y = e0.x * w0_##k1 + e0.y * w1_##k1 + e1.x * w2_##k1 + e1.y * w3_##k1; \
        __builtin_nontemporal_store(vA, reinterpret_cast<f32x2v*>(ocA + pxe));\
        __builtin_nontemporal_store(vB, reinterpret_cast<f32x2v*>(ocB + pxe));\
    } while (0)

    // Slow path (never taken for this data): global bilinear gather.
#define SPX2(k, ocA, ocB, chA) do {                                           \
        const int px = PXOF(k);                                               \
        const int gpx = pixbase + px;                                         \
        const int x = gpx & (W - 1);                                          \
        const int y = gpx >> 7;                                               \
        const int x0 = (int)floorf((float)x + fx_p[gpx]);                     \
        const int y0 = (int)floorf((float)y + fy_p[gpx]);                     \
        const int bx  = min(max(x0, 0), W - 2);                               \
        const int cy0 = min(max(y0, 0), H - 1);                               \
        const int cy1 = min(max(y0 + 1, 0), H - 1);                           \
        const float* fA = featb + (size_t)(chA) * HW;                         \
        const float* fB = fA + HW;                                            \
        ocA[px] = fA[cy0 * W + bx]     * w0_##k + fA[cy0 * W + bx + 1] * w1_##k\
                + fA[cy1 * W + bx]     * w2_##k + fA[cy1 * W + bx + 1] * w3_##k;\
        ocB[px] = fB[cy0 * W + bx]     * w0_##k + fB[cy0 * W + bx + 1] * w1_##k\
                + fB[cy1 * W + bx]     * w2_##k + fB[cy1 * W + bx + 1] * w3_##k;\
    } while (0)

    // ---- pair loop: DMA(p+1) || compute(p) ; counted vmcnt ; barrier
    for (int p = 0; p < CG / 2; ++p) {
        const int chA = 2 * p;
        if (p < CG / 2 - 1) PREF2((p + 1) & 1, chA + 2);

        const float* rbA = &rows[p & 1][0][0];
        const float* rbB = &rows[p & 1][1][0];
        float* ocA = outc + (size_t)chA * HW;
        float* ocB = ocA + HW;
        if (__builtin_expect(anybad, 0)) {
            SPX2(0, ocA, ocB, chA); SPX2(1, ocA, ocB, chA);
            SPX2(2, ocA, ocB, chA); SPX2(3, ocA, ocB, chA);
        } else {
            FQUAD(0, 0, 1, rbA, rbB, ocA, ocB);
            FQUAD(1, 2, 3, rbA, rbB, ocA, ocB);
        }

        if (p < CG / 2 - 1) {
            // Per-wave issue order: (<=4 prior stores) then 3 DMAs then 4 new
            // stores. vmcnt(4) drains prior stores + all DMAs, leaves the 4
            // current stores in flight (minimal correct wait).
            asm volatile("s_waitcnt vmcnt(4)" ::: "memory");
            __builtin_amdgcn_sched_barrier(0);
            __syncthreads();
        }
    }
#undef PREF2
#undef PXDECL
#undef PXOF
#undef WCOMP
#undef FQUAD
#undef SPX2
}

// ---------------------------------------------------------------------------
extern "C" void kernel_launch(void* const* d_in, const int* in_sizes, int n_in,
                              void* d_out, int out_size, void* d_ws, size_t ws_size,
                              hipStream_t stream)
{
    const float* features = (const float*)d_in[0];
    const float* flows    = (const float*)d_in[1];
    const float* conv_w   = (const float*)d_in[2];
    float*       out      = (float*)d_out;
    float*       f        = (float*)d_ws;   // [B,2,H,W] = 1 MiB

    downsample_kernel<<<1024, 256, 0, stream>>>(flows, conv_w, f);
    // B * RGN * CGN = 8 * 8 * 8 = 512 blocks of 512 threads
    warp_kernel<<<512, NT, 0, stream>>>(features, f, out);
}

// Round 24
// 49.779 us; speedup vs baseline: 2.8731x; 1.0210x over previous
//
#include <hip/hip_runtime.h>

// Problem constants (fixed by setup_inputs)
#define B   8
#define C   256
#define H   128
#define W   128
#define HW  (H * W)
#define FH  512
#define FW  512

// Tiling
#define TR     16              // output rows per tile
#define SLOTS  24              // staged row slots (= 12 wave-chunks of 2 rows)
#define HALO   3               // rows staged above tile: row0 = ybase-3
#define CG     32              // channels per block (16 pairs)
#define RGN    (H / TR)        // 8 row-groups
#define CGN    (C / CG)        // 8 channel-groups
#define NT     512             // threads per block
#define NPAIR  (CG / 2)        // 16

// 8B LDS load at 4B alignment -> ds_read2_b32 (one instruction).
struct __attribute__((packed, aligned(4))) pf2 { float x, y; };
typedef float f32x2v __attribute__((ext_vector_type(2)));

// ---------------------------------------------------------------------------
// Kernel 1: strided 4x4 conv downsample of flows using runtime conv_w.
// ---------------------------------------------------------------------------
__global__ __launch_bounds__(256) void downsample_kernel(
    const float* __restrict__ flows,
    const float* __restrict__ conv_w,
    float* __restrict__ f)
{
    int idx = blockIdx.x * blockDim.x + threadIdx.x;
    if (idx >= B * 2 * H * W) return;
    int x = idx & (W - 1);
    int y = (idx >> 7) & (H - 1);
    int o = (idx >> 14) & 1;
    int b = idx >> 15;

    const float* fb = flows + (size_t)b * 2 * FH * FW;
    const float* cw = conv_w + o * 2 * 16;

    float acc = 0.f;
#pragma unroll
    for (int i = 0; i < 2; ++i) {
        const float* fi = fb + (size_t)i * FH * FW;
#pragma unroll
        for (int kh = 0; kh < 4; ++kh) {
            const float4 v = *reinterpret_cast<const float4*>(
                fi + (size_t)(4 * y + kh) * FW + 4 * x);
            const float* w = cw + i * 16 + kh * 4;
            acc += v.x * w[0] + v.y * w[1] + v.z * w[2] + v.w * w[3];
        }
    }
    f[idx] = acc;
}

// ---------------------------------------------------------------------------
// Kernel 2: bilinear warp. R23 pair-pipeline (CG=32, global_load_lds,
// 512 threads, x-pair f32x2 NT streaming) with THREE LDS super-buffers:
// PREF2 at iter p fills buf (p+2)%3, so each DMA has 2 compute phases of
// slack and the counted wait (vmcnt(11) steady) never drains stores younger
// than 2 iterations. Issue-order audit in comments at each wait.
// ---------------------------------------------------------------------------
#define GLOAD_LDS(gsrc, ldst)                                                 \
    __builtin_amdgcn_global_load_lds(                                         \
        (const __attribute__((address_space(1))) void*)(gsrc),                \
        (__attribute__((address_space(3))) void*)(ldst), 16, 0, 0)

__global__ __launch_bounds__(NT, 6) void warp_kernel(
    const float* __restrict__ feat,
    const float* __restrict__ f,
    float* __restrict__ out)
{
    // [super-buffer 0..2][channel-within-pair][24 rows x 128] linear planes
    __shared__ __align__(16) float rows[3][2][SLOTS * W];  // 73728 B

    // XCD-chunked swizzle (512 blocks = 8 XCDs x 64), rg fastest.
    const int hw_bid = blockIdx.x;
    const int lin = (hw_bid & 7) * 64 + (hw_bid >> 3);
    const int rg = lin & (RGN - 1);
    const int cg = (lin >> 3) & (CGN - 1);
    const int b  = lin >> 6;

    const int tid  = threadIdx.x;
    const int lane = tid & 63;
    const int wv   = tid >> 6;          // 0..7
    const int wq   = wv & 3;            // wave within channel-half
    const int half = wv >> 2;           // 0: channel A, 1: channel B

    const int ybase = rg * TR;
    const int row0  = ybase - HALO;
    const int pixbase = ybase * W;

    const float* featb = feat + ((size_t)b * C + (size_t)cg * CG) * HW;
    float*       outc  = out  + ((size_t)b * C + (size_t)cg * CG) * HW + pixbase;
    const float* fx_p  = f + (size_t)(b * 2 + 0) * HW;
    const float* fy_p  = f + (size_t)(b * 2 + 1) * HW;

    // Per-lane global source offsets for this wave's 3 staging chunks.
    int goffs0, goffs1, goffs2;
    {
        const int wc0 = wq * 3 + 0, wc1 = wq * 3 + 1, wc2 = wq * 3 + 2;
        const int r0c = min(max(row0 + 2 * wc0 + (lane >> 5), 0), H - 1);
        const int r1c = min(max(row0 + 2 * wc1 + (lane >> 5), 0), H - 1);
        const int r2c = min(max(row0 + 2 * wc2 + (lane >> 5), 0), H - 1);
        goffs0 = r0c * W + (lane & 31) * 4;
        goffs1 = r1c * W + (lane & 31) * 4;
        goffs2 = r2c * W + (lane & 31) * 4;
    }

#define PREF2(s, chA) do {                                                    \
        const float* _cb = featb + (size_t)((chA) + half) * HW;               \
        float* _pl = &rows[(s)][half][0];                                     \
        GLOAD_LDS(_cb + goffs0, _pl + (wq * 3 + 0) * 256);                    \
        GLOAD_LDS(_cb + goffs1, _pl + (wq * 3 + 1) * 256);                    \
        GLOAD_LDS(_cb + goffs2, _pl + (wq * 3 + 2) * 256);                    \
    } while (0)

    // ---- prologue: pairs 0 and 1 in flight; weights -> registers meanwhile
    PREF2(0, 0);
    PREF2(1, 2);

    // Pixel mapping: k=0 -> 2t, k=1 -> 2t+1, k=2 -> 1024+2t, k=3 -> 1025+2t.
#define PXOF(k) (((k) >> 1) * 1024 + 2 * tid + ((k) & 1))

    // Named per-pixel state (no arrays -> guaranteed registers).
#define PXDECL(k) int i0_##k, i1_##k; float w0_##k, w1_##k, w2_##k, w3_##k;
    PXDECL(0) PXDECL(1) PXDECL(2) PXDECL(3)

#define WCOMP(k) do {                                                         \
        const int px  = PXOF(k);                                              \
        const int gpx = pixbase + px;                                         \
        const int x = gpx & (W - 1);                                          \
        const int y = gpx >> 7;                                               \
        const float gx = (float)x + fx_p[gpx];                                \
        const float gy = (float)y + fy_p[gpx];                                \
        const float x0f = floorf(gx);                                         \
        const float y0f = floorf(gy);                                         \
        const float wx = gx - x0f;                                            \
        const float wy = gy - y0f;                                            \
        const int x0 = (int)x0f, y0 = (int)y0f;                               \
        const int y1 = y0 + 1;                                                \
        const float u0 = 1.f - wx, u1 = wx;                                   \
        float A, Bv;                                                          \
        if (x0 >= 0 && x0 <= W - 2)      { A = u0;  Bv = u1;  }               \
        else if (x0 == W - 1)            { A = 0.f; Bv = u0;  }               \
        else if (x0 == -1)               { A = u1;  Bv = 0.f; }               \
        else                             { A = 0.f; Bv = 0.f; }               \
        const int bx = min(max(x0, 0), W - 2);                                \
        const float vy0 = (y0 >= 0 && y0 < H) ? 1.f : 0.f;                    \
        const float vy1 = (y1 >= 0 && y1 < H) ? 1.f : 0.f;                    \
        const int cy0 = min(max(y0, 0), H - 1);                               \
        const int cy1 = min(max(y1, 0), H - 1);                               \
        const int s0 = cy0 - row0;                                            \
        const int s1 = cy1 - row0;                                            \
        const bool ok = (s0 >= 0) && (s1 < SLOTS);                            \
        const int cs0 = min(max(s0, 0), SLOTS - 1);                           \
        const int cs1 = min(max(s1, 0), SLOTS - 1);                           \
        i0_##k = (cs0 * W + bx) | (ok ? 0 : (int)0x80000000);                 \
        i1_##k = cs1 * W + bx;                                                \
        const float wy0 = (1.f - wy) * vy0;                                   \
        const float wy1 = wy * vy1;                                           \
        w0_##k = A * wy0;  w1_##k = Bv * wy0;                                 \
        w2_##k = A * wy1;  w3_##k = Bv * wy1;                                 \
    } while (0)

    WCOMP(0); WCOMP(1); WCOMP(2); WCOMP(3);

    const int anybad = ((i0_0 | i0_1 | i0_2 | i0_3) < 0);

    // Prologue wait: outstanding = DMA(pair0)x3, DMA(pair1)x3. vmcnt(3)
    // drains pair0's DMAs, leaves pair1's 3 in flight.
    asm volatile("s_waitcnt vmcnt(3)" ::: "memory");
    __builtin_amdgcn_sched_barrier(0);
    __syncthreads();

    // Fast path, one x-pair (j=0 -> k0,k1 at px 2t; j=1 -> k2,k3 at 1024+2t):
    // 8 paired LDS taps -> 2 NT f32x2 stores (A and B channels).
#define FQUAD(j, k0, k1, rbA, rbB, ocA, ocB) do {                             \
        const int pxe = (j) * 1024 + 2 * tid;                                 \
        const pf2 a0 = *reinterpret_cast<const pf2*>(&rbA[i0_##k0]);          \
        const pf2 a1 = *reinterpret_cast<const pf2*>(&rbA[i1_##k0]);          \
        const pf2 c0 = *reinterpret_cast<const pf2*>(&rbA[i0_##k1]);          \
        const pf2 c1 = *reinterpret_cast<const pf2*>(&rbA[i1_##k1]);          \
        const pf2 d0 = *reinterpret_cast<const pf2*>(&rbB[i0_##k0]);          \
        const pf2 d1 = *reinterpret_cast<const pf2*>(&rbB[i1_##k0]);          \
        const pf2 e0 = *reinterpret_cast<const pf2*>(&rbB[i0_##k1]);          \
        const pf2 e1 = *reinterpret_cast<const pf2*>(&rbB[i1_##k1]);          \
        f32x2v vA, vB;                                                        \
        vA.x = a0.x * w0_##k0 + a0.y * w1_##k0 + a1.x * w2_##k0 + a1.y * w3_##k0; \
        vA.y = c0.x * w0_##k1 + c0.y * w1_##k1 + c1.x * w2_##k1 + c1.y * w3_##k1; \
        vB.x = d0.x * w0_##k0 + d0.y * w1_##k0 + d1.x * w2_##k0 + d1.y * w3_##k0; \
        vB.y = e0.x * w0_##k1 + e0.y * w1_##k1 + e1.x * w2_##k1 + e1.y * w3_##k1; \
        __builtin_nontemporal_store(vA, reinterpret_cast<f32x2v*>(ocA + pxe));\
        __builtin_nontemporal_store(vB, reinterpret_cast<f32x2v*>(ocB + pxe));\
    } while (0)

    // Slow path (never taken for this data): global bilinear gather.
#define SPX2(k, ocA, ocB, chA) do {                                           \
        const int px = PXOF(k);                                               \
        const int gpx = pixbase + px;                                         \
        const int x = gpx & (W - 1);                                          \
        const int y = gpx >> 7;                                               \
        const int x0 = (int)floorf((float)x + fx_p[gpx]);                     \
        const int y0 = (int)floorf((float)y + fy_p[gpx]);                     \
        const int bx  = min(max(x0, 0), W - 2);                               \
        const int cy0 = min(max(y0, 0), H - 1);                               \
        const int cy1 = min(max(y0 + 1, 0), H - 1);                           \
        const float* fA = featb + (size_t)(chA) * HW;                         \
        const float* fB = fA + HW;                                            \
        ocA[px] = fA[cy0 * W + bx]     * w0_##k + fA[cy0 * W + bx + 1] * w1_##k\
                + fA[cy1 * W + bx]     * w2_##k + fA[cy1 * W + bx + 1] * w3_##k;\
        ocB[px] = fB[cy0 * W + bx]     * w0_##k + fB[cy0 * W + bx + 1] * w1_##k\
                + fB[cy1 * W + bx]     * w2_##k + fB[cy1 * W + bx + 1] * w3_##k;\
    } while (0)

    // ---- pair loop: DMA(p+2 -> buf (p+2)%3) || compute(p from buf p%3)
    // buf (p+2)%3 was last read at iter p-1; that iteration's end barrier
    // precedes this PREF2, so the overwrite is safe.
    for (int p = 0; p < NPAIR; ++p) {
        const int chA = 2 * p;
        if (p < NPAIR - 2) PREF2((p + 2) % 3, chA + 4);

        const float* rbA = &rows[p % 3][0][0];
        const float* rbB = &rows[p % 3][1][0];
        float* ocA = outc + (size_t)chA * HW;
        float* ocB = ocA + HW;
        if (__builtin_expect(anybad, 0)) {
            SPX2(0, ocA, ocB, chA); SPX2(1, ocA, ocB, chA);
            SPX2(2, ocA, ocB, chA); SPX2(3, ocA, ocB, chA);
        } else {
            FQUAD(0, 0, 1, rbA, rbB, ocA, ocB);
            FQUAD(1, 2, 3, rbA, rbB, ocA, ocB);
        }

        if (p == 0) {
            // Outstanding: DMA(p1)x3 already drained? No: prologue left
            // DMA(p1)x3; this iter added DMA(p2)x3 + store(0)x4 = 10.
            // Need DMA(p1) done -> vmcnt(7) (leaves DMA(p2)3 + store(0)4).
            asm volatile("s_waitcnt vmcnt(7)" ::: "memory");
            __builtin_amdgcn_sched_barrier(0);
            __syncthreads();
        } else if (p < NPAIR - 2) {
            // Steady state outstanding (oldest first): store(p-2)x4 [maybe
            // retired], DMA(p+1)x3, store(p-1)x4, DMA(p+2)x3, store(p)x4.
            // Need DMA(p+1) done -> vmcnt(11): drains the 7 oldest, leaves
            // store(p-1)4 + DMA(p+2)3 + store(p)4. Stores are only ever
            // force-drained at age >= 2 iterations.
            asm volatile("s_waitcnt vmcnt(11)" ::: "memory");
            __builtin_amdgcn_sched_barrier(0);
            __syncthreads();
        } else if (p == NPAIR - 2) {
            // No PREF this iter. Outstanding: store(p-2)x4, DMA(p+1)x3,
            // store(p-1)x4, store(p)x4 = 15. Need DMA(p+1) -> vmcnt(8).
            asm volatile("s_waitcnt vmcnt(8)" ::: "memory");
            __builtin_amdgcn_sched_barrier(0);
            __syncthreads();
        }
        // p == NPAIR-1: last pair, no wait/barrier needed.
    }
#undef PREF2
#undef PXDECL
#undef PXOF
#undef WCOMP
#undef FQUAD
#undef SPX2
}

// ---------------------------------------------------------------------------
extern "C" void kernel_launch(void* const* d_in, const int* in_sizes, int n_in,
                              void* d_out, int out_size, void* d_ws, size_t ws_size,
                              hipStream_t stream)
{
    const float* features = (const float*)d_in[0];
    const float* flows    = (const float*)d_in[1];
    const float* conv_w   = (const float*)d_in[2];
    float*       out      = (float*)d_out;
    float*       f        = (float*)d_ws;   // [B,2,H,W] = 1 MiB

    downsample_kernel<<<1024, 256, 0, stream>>>(flows, conv_w, f);
    // B * RGN * CGN = 8 * 8 * 8 = 512 blocks of 512 threads
    warp_kernel<<<512, NT, 0, stream>>>(features, f, out);
}